// Round 1
// baseline (1282.413 us; speedup 1.0000x reference)
//
#include <hip/hip_runtime.h>

// Inverse-CDF categorical sampler:
//   out[row] = #{ v : cumsum(p[row])[v] < rng[row] }
// B*T = 8192 rows, V = 32000 categories.
// One block of 256 threads per row; coalesced float4 streaming with
// hierarchical (wave-shuffle + LDS) inclusive scan per 1024-elem tile,
// carry across tiles, per-element strict compare against rng.

constexpr int V = 32000;
constexpr int FULL_TILES = 31;        // 31 * 1024 = 31744
constexpr int TAIL_BASE = FULL_TILES * 1024;  // 31744, tail = 256 scalars

__global__ __launch_bounds__(256) void sampler_kernel(
    const float* __restrict__ p,
    const float* __restrict__ rng,
    int* __restrict__ out)
{
    const int row  = blockIdx.x;
    const int tid  = threadIdx.x;
    const int lane = tid & 63;
    const int wave = tid >> 6;

    const float r = rng[row];
    const float4* prow4 = reinterpret_cast<const float4*>(p + (size_t)row * V);

    __shared__ float wsum[4];
    __shared__ int   cpart[4];

    float carry = 0.0f;
    int count = 0;

    for (int tile = 0; tile < FULL_TILES; ++tile) {
        // coalesced: thread tid owns float4 index tile*256 + tid
        float4 x = prow4[tile * 256 + tid];
        float s = (x.x + x.y) + (x.z + x.w);

        // wave-level inclusive scan over 64 lanes
        float scan = s;
        #pragma unroll
        for (int off = 1; off < 64; off <<= 1) {
            float n = __shfl_up(scan, off, 64);
            if (lane >= off) scan += n;
        }
        if (lane == 63) wsum[wave] = scan;
        __syncthreads();

        float waveBase = 0.0f, tileTotal = 0.0f;
        #pragma unroll
        for (int w = 0; w < 4; ++w) {
            float t = wsum[w];
            if (w < wave) waveBase += t;
            tileTotal += t;
        }

        // exclusive prefix for this thread's 4 elements
        float run = carry + waveBase + (scan - s);
        run += x.x; count += (run < r);
        run += x.y; count += (run < r);
        run += x.z; count += (run < r);
        run += x.w; count += (run < r);

        carry += tileTotal;
        __syncthreads();   // protect wsum before next tile overwrites it
    }

    // tail: 256 scalar elements (one per thread)
    {
        float xv = p[(size_t)row * V + TAIL_BASE + tid];
        float scan = xv;
        #pragma unroll
        for (int off = 1; off < 64; off <<= 1) {
            float n = __shfl_up(scan, off, 64);
            if (lane >= off) scan += n;
        }
        if (lane == 63) wsum[wave] = scan;
        __syncthreads();

        float waveBase = 0.0f;
        #pragma unroll
        for (int w = 0; w < 4; ++w) {
            if (w < wave) waveBase += wsum[w];
        }
        float excl = carry + waveBase + (scan - xv);
        count += ((excl + xv) < r);
    }

    // block-level reduction of per-thread counts
    #pragma unroll
    for (int off = 32; off > 0; off >>= 1)
        count += __shfl_down(count, off, 64);
    if (lane == 0) cpart[wave] = count;
    __syncthreads();
    if (tid == 0)
        out[row] = cpart[0] + cpart[1] + cpart[2] + cpart[3];
}

extern "C" void kernel_launch(void* const* d_in, const int* in_sizes, int n_in,
                              void* d_out, int out_size, void* d_ws, size_t ws_size,
                              hipStream_t stream) {
    const float* p   = (const float*)d_in[0];
    const float* rng = (const float*)d_in[1];
    int* out = (int*)d_out;
    const int rows = in_sizes[1];   // B*T = 8192
    sampler_kernel<<<rows, 256, 0, stream>>>(p, rng, out);
}